// Round 1
// baseline (5012.979 us; speedup 1.0000x reference)
//
#include <hip/hip_runtime.h>

#define N_NODES 100000
#define N_EDGES 3200000
#define C 50
#define C3 150
#define NC (N_NODES * C)

// m[n,c] = sum_k h[n,k] * W[k,c]   (W: [C,C] row-major)
__global__ __launch_bounds__(256) void conv_kernel(const float* __restrict__ h,
                                                   const float* __restrict__ W,
                                                   float* __restrict__ m) {
    __shared__ float sW[C * C];
    for (int i = threadIdx.x; i < C * C; i += 256) sW[i] = W[i];
    __syncthreads();
    int t = blockIdx.x * 256 + threadIdx.x;
    if (t >= NC) return;
    int n = t / C, c = t - n * C;
    const float* hr = h + n * C;
    float acc = 0.f;
#pragma unroll
    for (int k = 0; k < C; ++k) acc = fmaf(hr[k], sW[k * C + c], acc);
    m[t] = acc;
}

// For each edge e: agg[dst[e], :] += m[src[e], :].  2 channels per thread.
__global__ __launch_bounds__(256) void scatter_kernel(const float* __restrict__ m,
                                                      const int* __restrict__ ei,
                                                      float* __restrict__ agg) {
    int t = blockIdx.x * 256 + threadIdx.x;
    if (t >= N_EDGES * 25) return;
    int e = t / 25, c2 = t - e * 25;
    int s = ei[e];             // src row
    int d = ei[N_EDGES + e];   // dst row
    const float2 v = *reinterpret_cast<const float2*>(m + s * C + c2 * 2);
    atomicAdd(agg + d * C + c2 * 2 + 0, v.x);
    atomicAdd(agg + d * C + c2 * 2 + 1, v.y);
}

// GRUCell: one thread per (node, out-channel)
__global__ __launch_bounds__(256) void gru_kernel(const float* __restrict__ agg,
                                                  const float* __restrict__ h,
                                                  const float* __restrict__ w_ih,
                                                  const float* __restrict__ w_hh,
                                                  const float* __restrict__ b_ih,
                                                  const float* __restrict__ b_hh,
                                                  float* __restrict__ hout) {
    __shared__ float s_wih[C3 * C];   // 30 KB
    __shared__ float s_whh[C3 * C];   // 30 KB
    for (int i = threadIdx.x; i < C3 * C; i += 256) {
        s_wih[i] = w_ih[i];
        s_whh[i] = w_hh[i];
    }
    __syncthreads();
    int t = blockIdx.x * 256 + threadIdx.x;
    if (t >= NC) return;
    int n = t / C, c = t - n * C;
    const float* ar = agg + n * C;
    const float* hr = h + n * C;
    float ir = 0.f, iz = 0.f, inn = 0.f, hr_ = 0.f, hz = 0.f, hn = 0.f;
#pragma unroll
    for (int k = 0; k < C; ++k) {
        float a = ar[k], hv = hr[k];
        ir  = fmaf(a,  s_wih[c * C + k],            ir);
        iz  = fmaf(a,  s_wih[(C + c) * C + k],      iz);
        inn = fmaf(a,  s_wih[(2 * C + c) * C + k],  inn);
        hr_ = fmaf(hv, s_whh[c * C + k],            hr_);
        hz  = fmaf(hv, s_whh[(C + c) * C + k],      hz);
        hn  = fmaf(hv, s_whh[(2 * C + c) * C + k],  hn);
    }
    ir  += b_ih[c];         hr_ += b_hh[c];
    iz  += b_ih[C + c];     hz  += b_hh[C + c];
    inn += b_ih[2 * C + c]; hn  += b_hh[2 * C + c];
    float r = 1.f / (1.f + expf(-(ir + hr_)));
    float z = 1.f / (1.f + expf(-(iz + hz)));
    float nn = tanhf(inn + r * hn);
    hout[t] = (1.f - z) * nn + z * hr[c];
}

// out[n,c] = sum_k relu(h[n,k]) * lin_w[c,k] + lin_b[c]
__global__ __launch_bounds__(256) void out_kernel(const float* __restrict__ h,
                                                  const float* __restrict__ lin_w,
                                                  const float* __restrict__ lin_b,
                                                  float* __restrict__ out) {
    __shared__ float sW[C * C];
    for (int i = threadIdx.x; i < C * C; i += 256) sW[i] = lin_w[i];
    __syncthreads();
    int t = blockIdx.x * 256 + threadIdx.x;
    if (t >= NC) return;
    int n = t / C, c = t - n * C;
    const float* hr = h + n * C;
    float acc = lin_b[c];
#pragma unroll
    for (int k = 0; k < C; ++k) {
        float v = hr[k];
        v = v > 0.f ? v : 0.f;
        acc = fmaf(v, sW[c * C + k], acc);
    }
    out[t] = acc;
}

extern "C" void kernel_launch(void* const* d_in, const int* in_sizes, int n_in,
                              void* d_out, int out_size, void* d_ws, size_t ws_size,
                              hipStream_t stream) {
    const float* x      = (const float*)d_in[0];
    const int*   ei     = (const int*)  d_in[1];   // [2, E]
    // d_in[2] edge_attr: unused by reference forward
    const float* conv_w = (const float*)d_in[3];   // [3, C, C]
    const float* w_ih   = (const float*)d_in[4];   // [3C, C]
    const float* w_hh   = (const float*)d_in[5];   // [3C, C]
    const float* b_ih   = (const float*)d_in[6];
    const float* b_hh   = (const float*)d_in[7];
    // d_in[8] edge_emb: unused
    const float* lin_w  = (const float*)d_in[9];   // [C, C]
    const float* lin_b  = (const float*)d_in[10];
    float* out = (float*)d_out;

    float* ws  = (float*)d_ws;
    float* m   = ws;            // 5M floats
    float* agg = ws + NC;       // 5M
    float* h_a = ws + 2 * NC;   // 5M
    float* h_b = ws + 3 * NC;   // 5M

    const int nodeBlocks = (NC + 255) / 256;
    const int edgeBlocks = (N_EDGES * 25 + 255) / 256;

    const float* h_in = x;
    float* h_outs[3] = {h_a, h_b, h_a};
    for (int l = 0; l < 3; ++l) {
        conv_kernel<<<nodeBlocks, 256, 0, stream>>>(h_in, conv_w + l * C * C, m);
        hipMemsetAsync(agg, 0, (size_t)NC * sizeof(float), stream);
        scatter_kernel<<<edgeBlocks, 256, 0, stream>>>(m, ei, agg);
        gru_kernel<<<nodeBlocks, 256, 0, stream>>>(agg, h_in, w_ih, w_hh, b_ih, b_hh, h_outs[l]);
        h_in = h_outs[l];
    }
    out_kernel<<<nodeBlocks, 256, 0, stream>>>(h_in, lin_w, lin_b, out);
}

// Round 8
// 1629.847 us; speedup vs baseline: 3.0757x; 3.0757x over previous
//
#include <hip/hip_runtime.h>

#define N_NODES 100000
#define N_EDGES 3200000
#define C 50
#define C3 150
#define NC (N_NODES * C)
#define SCAN_BLOCKS ((N_NODES + 255) / 256)   // 391

// ---------------- CSR build ----------------

__global__ __launch_bounds__(256) void deg_kernel(const int* __restrict__ ei,
                                                  int* __restrict__ deg) {
    int e = blockIdx.x * 256 + threadIdx.x;
    if (e < N_EDGES) atomicAdd(&deg[ei[N_EDGES + e]], 1);
}

// exclusive scan, phase 1: per-block scan of deg -> rowptr(partial) + blockSums
__global__ __launch_bounds__(256) void scan1_kernel(const int* __restrict__ deg,
                                                    int* __restrict__ rowptr,
                                                    int* __restrict__ blockSums) {
    __shared__ int buf[256];
    int gid = blockIdx.x * 256 + threadIdx.x;
    int v = (gid < N_NODES) ? deg[gid] : 0;
    buf[threadIdx.x] = v;
    __syncthreads();
    for (int off = 1; off < 256; off <<= 1) {
        int t = (threadIdx.x >= off) ? buf[threadIdx.x - off] : 0;
        __syncthreads();
        buf[threadIdx.x] += t;
        __syncthreads();
    }
    if (gid < N_NODES) rowptr[gid] = buf[threadIdx.x] - v;   // exclusive
    if (threadIdx.x == 255) blockSums[blockIdx.x] = buf[255];
}

// phase 2: single-block exclusive scan of blockSums (391 entries)
__global__ __launch_bounds__(512) void scan2_kernel(int* __restrict__ blockSums) {
    __shared__ int buf[512];
    int v = (threadIdx.x < SCAN_BLOCKS) ? blockSums[threadIdx.x] : 0;
    buf[threadIdx.x] = v;
    __syncthreads();
    for (int off = 1; off < 512; off <<= 1) {
        int t = (threadIdx.x >= off) ? buf[threadIdx.x - off] : 0;
        __syncthreads();
        buf[threadIdx.x] += t;
        __syncthreads();
    }
    if (threadIdx.x < SCAN_BLOCKS) blockSums[threadIdx.x] = buf[threadIdx.x] - v;
}

// phase 3: add block offsets; init cursor = rowptr
__global__ __launch_bounds__(256) void scan3_kernel(int* __restrict__ rowptr,
                                                    const int* __restrict__ blockSums,
                                                    int* __restrict__ cursor) {
    int gid = blockIdx.x * 256 + threadIdx.x;
    if (gid < N_NODES) {
        int r = rowptr[gid] + blockSums[blockIdx.x];
        rowptr[gid] = r;
        cursor[gid] = r;
    }
    if (gid == 0) rowptr[N_NODES] = N_EDGES;
}

__global__ __launch_bounds__(256) void fill_kernel(const int* __restrict__ ei,
                                                   int* __restrict__ cursor,
                                                   int* __restrict__ col) {
    int e = blockIdx.x * 256 + threadIdx.x;
    if (e < N_EDGES) {
        int d = ei[N_EDGES + e];
        int pos = atomicAdd(&cursor[d], 1);
        col[pos] = ei[e];   // src
    }
}

// ---------------- per-layer kernels ----------------

// m[n,c] = sum_k h[n,k] * W[k,c]   (W: [C,C] row-major)
__global__ __launch_bounds__(256) void conv_kernel(const float* __restrict__ h,
                                                   const float* __restrict__ W,
                                                   float* __restrict__ m) {
    __shared__ float sW[C * C];
    for (int i = threadIdx.x; i < C * C; i += 256) sW[i] = W[i];
    __syncthreads();
    int t = blockIdx.x * 256 + threadIdx.x;
    if (t >= NC) return;
    int n = t / C, c = t - n * C;
    const float* hr = h + n * C;
    float acc = 0.f;
#pragma unroll
    for (int k = 0; k < C; ++k) acc = fmaf(hr[k], sW[k * C + c], acc);
    m[t] = acc;
}

// wave-per-node CSR gather: agg[n,:] = sum_{e in rowptr[n]..} m[col[e],:]
__global__ __launch_bounds__(256) void gather_kernel(const float* __restrict__ m,
                                                     const int* __restrict__ rowptr,
                                                     const int* __restrict__ col,
                                                     float* __restrict__ agg) {
    int w = (blockIdx.x * 256 + threadIdx.x) >> 6;   // node
    int lane = threadIdx.x & 63;
    if (w >= N_NODES) return;
    int start = rowptr[w], end = rowptr[w + 1];
    float acc = 0.f;
    int e = start;
    for (; e + 3 < end; e += 4) {
        int s0 = col[e], s1 = col[e + 1], s2 = col[e + 2], s3 = col[e + 3];
        if (lane < C) {
            float v0 = m[s0 * C + lane];
            float v1 = m[s1 * C + lane];
            float v2 = m[s2 * C + lane];
            float v3 = m[s3 * C + lane];
            acc += (v0 + v1) + (v2 + v3);
        }
    }
    for (; e < end; ++e) {
        int s = col[e];
        if (lane < C) acc += m[s * C + lane];
    }
    if (lane < C) agg[w * C + lane] = acc;
}

// GRUCell: one thread per (node, out-channel)
__global__ __launch_bounds__(256) void gru_kernel(const float* __restrict__ agg,
                                                  const float* __restrict__ h,
                                                  const float* __restrict__ w_ih,
                                                  const float* __restrict__ w_hh,
                                                  const float* __restrict__ b_ih,
                                                  const float* __restrict__ b_hh,
                                                  float* __restrict__ hout) {
    __shared__ float s_wih[C3 * C];   // 30 KB
    __shared__ float s_whh[C3 * C];   // 30 KB
    for (int i = threadIdx.x; i < C3 * C; i += 256) {
        s_wih[i] = w_ih[i];
        s_whh[i] = w_hh[i];
    }
    __syncthreads();
    int t = blockIdx.x * 256 + threadIdx.x;
    if (t >= NC) return;
    int n = t / C, c = t - n * C;
    const float* ar = agg + n * C;
    const float* hr = h + n * C;
    float ir = 0.f, iz = 0.f, inn = 0.f, hr_ = 0.f, hz = 0.f, hn = 0.f;
#pragma unroll
    for (int k = 0; k < C; ++k) {
        float a = ar[k], hv = hr[k];
        ir  = fmaf(a,  s_wih[c * C + k],            ir);
        iz  = fmaf(a,  s_wih[(C + c) * C + k],      iz);
        inn = fmaf(a,  s_wih[(2 * C + c) * C + k],  inn);
        hr_ = fmaf(hv, s_whh[c * C + k],            hr_);
        hz  = fmaf(hv, s_whh[(C + c) * C + k],      hz);
        hn  = fmaf(hv, s_whh[(2 * C + c) * C + k],  hn);
    }
    ir  += b_ih[c];         hr_ += b_hh[c];
    iz  += b_ih[C + c];     hz  += b_hh[C + c];
    inn += b_ih[2 * C + c]; hn  += b_hh[2 * C + c];
    float r = 1.f / (1.f + expf(-(ir + hr_)));
    float z = 1.f / (1.f + expf(-(iz + hz)));
    float nn = tanhf(inn + r * hn);
    hout[t] = (1.f - z) * nn + z * hr[c];
}

// out[n,c] = sum_k relu(h[n,k]) * lin_w[c,k] + lin_b[c]
__global__ __launch_bounds__(256) void out_kernel(const float* __restrict__ h,
                                                  const float* __restrict__ lin_w,
                                                  const float* __restrict__ lin_b,
                                                  float* __restrict__ out) {
    __shared__ float sW[C * C];
    for (int i = threadIdx.x; i < C * C; i += 256) sW[i] = lin_w[i];
    __syncthreads();
    int t = blockIdx.x * 256 + threadIdx.x;
    if (t >= NC) return;
    int n = t / C, c = t - n * C;
    const float* hr = h + n * C;
    float acc = lin_b[c];
#pragma unroll
    for (int k = 0; k < C; ++k) {
        float v = hr[k];
        v = v > 0.f ? v : 0.f;
        acc = fmaf(v, sW[c * C + k], acc);
    }
    out[t] = acc;
}

extern "C" void kernel_launch(void* const* d_in, const int* in_sizes, int n_in,
                              void* d_out, int out_size, void* d_ws, size_t ws_size,
                              hipStream_t stream) {
    const float* x      = (const float*)d_in[0];
    const int*   ei     = (const int*)  d_in[1];   // [2, E]
    const float* conv_w = (const float*)d_in[3];   // [3, C, C]
    const float* w_ih   = (const float*)d_in[4];
    const float* w_hh   = (const float*)d_in[5];
    const float* b_ih   = (const float*)d_in[6];
    const float* b_hh   = (const float*)d_in[7];
    const float* lin_w  = (const float*)d_in[9];
    const float* lin_b  = (const float*)d_in[10];
    float* out = (float*)d_out;

    float* ws   = (float*)d_ws;
    float* bufX = ws;                 // 5M floats
    float* bufY = ws + NC;            // 5M
    float* bufZ = ws + 2 * NC;        // 5M
    int* col       = (int*)(ws + 3 * NC);        // 3.2M
    int* rowptr    = col + N_EDGES;              // 100001
    int* cursor    = rowptr + N_NODES + 1;       // 100001  (also deg)
    int* blockSums = cursor + N_NODES + 1;       // 391

    const int nodeBlocks = (NC + 255) / 256;
    const int edgeBlocks = (N_EDGES + 255) / 256;
    const int waveBlocks = (N_NODES * 64 + 255) / 256;

    // ---- CSR build (deg lives in `cursor`) ----
    hipMemsetAsync(cursor, 0, (size_t)(N_NODES + 1) * sizeof(int), stream);
    deg_kernel<<<edgeBlocks, 256, 0, stream>>>(ei, cursor);
    scan1_kernel<<<SCAN_BLOCKS, 256, 0, stream>>>(cursor, rowptr, blockSums);
    scan2_kernel<<<1, 512, 0, stream>>>(blockSums);
    scan3_kernel<<<SCAN_BLOCKS, 256, 0, stream>>>(rowptr, blockSums, cursor);
    fill_kernel<<<edgeBlocks, 256, 0, stream>>>(ei, cursor, col);

    // ---- 3 layers, buffer rotation: h0=x ----
    // L1: conv(x->X); gather(X->Y); gru(Y,x->Z)
    conv_kernel<<<nodeBlocks, 256, 0, stream>>>(x, conv_w + 0 * C * C, bufX);
    gather_kernel<<<waveBlocks, 256, 0, stream>>>(bufX, rowptr, col, bufY);
    gru_kernel<<<nodeBlocks, 256, 0, stream>>>(bufY, x, w_ih, w_hh, b_ih, b_hh, bufZ);
    // L2: conv(Z->X); gather(X->Y); gru(Y,Z->X)
    conv_kernel<<<nodeBlocks, 256, 0, stream>>>(bufZ, conv_w + 1 * C * C, bufX);
    gather_kernel<<<waveBlocks, 256, 0, stream>>>(bufX, rowptr, col, bufY);
    gru_kernel<<<nodeBlocks, 256, 0, stream>>>(bufY, bufZ, w_ih, w_hh, b_ih, b_hh, bufX);
    // L3: conv(X->Z); gather(Z->Y); gru(Y,X->Z)
    conv_kernel<<<nodeBlocks, 256, 0, stream>>>(bufX, conv_w + 2 * C * C, bufZ);
    gather_kernel<<<waveBlocks, 256, 0, stream>>>(bufZ, rowptr, col, bufY);
    gru_kernel<<<nodeBlocks, 256, 0, stream>>>(bufY, bufX, w_ih, w_hh, b_ih, b_hh, bufZ);

    out_kernel<<<nodeBlocks, 256, 0, stream>>>(bufZ, lin_w, lin_b, out);
}

// Round 9
// 1602.586 us; speedup vs baseline: 3.1281x; 1.0170x over previous
//
#include <hip/hip_runtime.h>

#define N_NODES 100000
#define N_EDGES 3200000
#define C 50
#define PC 56          // padded row: 224 B = exactly 4 cache lines
#define C3 150
#define NC (N_NODES * C)
#define NCP (N_NODES * PC)
#define SCAN_BLOCKS ((N_NODES + 255) / 256)   // 391

// ---------------- CSR build ----------------

__global__ __launch_bounds__(256) void deg_kernel(const int* __restrict__ ei,
                                                  int* __restrict__ deg) {
    int e = blockIdx.x * 256 + threadIdx.x;
    if (e < N_EDGES) atomicAdd(&deg[ei[N_EDGES + e]], 1);
}

__global__ __launch_bounds__(256) void scan1_kernel(const int* __restrict__ deg,
                                                    int* __restrict__ rowptr,
                                                    int* __restrict__ blockSums) {
    __shared__ int buf[256];
    int gid = blockIdx.x * 256 + threadIdx.x;
    int v = (gid < N_NODES) ? deg[gid] : 0;
    buf[threadIdx.x] = v;
    __syncthreads();
    for (int off = 1; off < 256; off <<= 1) {
        int t = (threadIdx.x >= off) ? buf[threadIdx.x - off] : 0;
        __syncthreads();
        buf[threadIdx.x] += t;
        __syncthreads();
    }
    if (gid < N_NODES) rowptr[gid] = buf[threadIdx.x] - v;   // exclusive
    if (threadIdx.x == 255) blockSums[blockIdx.x] = buf[255];
}

__global__ __launch_bounds__(512) void scan2_kernel(int* __restrict__ blockSums) {
    __shared__ int buf[512];
    int v = (threadIdx.x < SCAN_BLOCKS) ? blockSums[threadIdx.x] : 0;
    buf[threadIdx.x] = v;
    __syncthreads();
    for (int off = 1; off < 512; off <<= 1) {
        int t = (threadIdx.x >= off) ? buf[threadIdx.x - off] : 0;
        __syncthreads();
        buf[threadIdx.x] += t;
        __syncthreads();
    }
    if (threadIdx.x < SCAN_BLOCKS) blockSums[threadIdx.x] = buf[threadIdx.x] - v;
}

__global__ __launch_bounds__(256) void scan3_kernel(int* __restrict__ rowptr,
                                                    const int* __restrict__ blockSums,
                                                    int* __restrict__ cursor) {
    int gid = blockIdx.x * 256 + threadIdx.x;
    if (gid < N_NODES) {
        int r = rowptr[gid] + blockSums[blockIdx.x];
        rowptr[gid] = r;
        cursor[gid] = r;
    }
    if (gid == 0) rowptr[N_NODES] = N_EDGES;
}

__global__ __launch_bounds__(256) void fill_kernel(const int* __restrict__ ei,
                                                   int* __restrict__ cursor,
                                                   int* __restrict__ col) {
    int e = blockIdx.x * 256 + threadIdx.x;
    if (e < N_EDGES) {
        int d = ei[N_EDGES + e];
        int pos = atomicAdd(&cursor[d], 1);
        col[pos] = ei[e];   // src
    }
}

// ---------------- per-layer kernels ----------------

// m[n, c<50] = sum_k h[n,k] * W[k,c]; pad channels 50..55 zeroed (gather reads them)
__global__ __launch_bounds__(256) void conv_kernel(const float* __restrict__ h, int hs,
                                                   const float* __restrict__ W,
                                                   float* __restrict__ m) {
    __shared__ float sW[C * C];
    for (int i = threadIdx.x; i < C * C; i += 256) sW[i] = W[i];
    __syncthreads();
    int t = blockIdx.x * 256 + threadIdx.x;
    if (t >= NCP) return;
    int n = t / PC, c = t - n * PC;
    float acc = 0.f;
    if (c < C) {
        const float* hr = h + (size_t)n * hs;
#pragma unroll
        for (int k = 0; k < C; ++k) acc = fmaf(hr[k], sW[k * C + c], acc);
    }
    m[t] = acc;
}

// wave-per-node gather, 4 edges/iteration: lane = 16*j + q; group j handles one
// edge via float4 (13 active lanes cover 52 channels); cross-group shfl_xor reduce.
__global__ __launch_bounds__(256) void gather_kernel(const float* __restrict__ m,
                                                     const int* __restrict__ rowptr,
                                                     const int* __restrict__ col,
                                                     float* __restrict__ agg) {
    int w = (blockIdx.x * 256 + threadIdx.x) >> 6;   // node (wave-uniform)
    int lane = threadIdx.x & 63;
    if (w >= N_NODES) return;
    int start = rowptr[w], end = rowptr[w + 1];
    int j = lane >> 4, q = lane & 15;
    int choff = (q < 13) ? (q * 4) : 48;             // q>=13: safe in-row dup
    bool qok = (q < 13);
    float4 acc = make_float4(0.f, 0.f, 0.f, 0.f);

    for (int base = start; base < end; base += 64) {
        int cidx = base + lane;
        int cols = col[cidx < N_EDGES ? cidx : (N_EDGES - 1)];  // coalesced chunk
        int cnt = end - base; if (cnt > 64) cnt = 64;
        int nt = (cnt + 3) >> 2;
#pragma unroll 4
        for (int t = 0; t < nt; ++t) {
            int rel = 4 * t + j;
            int s = __shfl(cols, rel);
            bool valid = qok && (rel < cnt);
            const float4 v = *reinterpret_cast<const float4*>(m + (size_t)s * PC + choff);
            acc.x += valid ? v.x : 0.f;
            acc.y += valid ? v.y : 0.f;
            acc.z += valid ? v.z : 0.f;
            acc.w += valid ? v.w : 0.f;
        }
    }
    // reduce across the 4 groups (lanes l, l^16, l^32, l^48)
    acc.x += __shfl_xor(acc.x, 16); acc.y += __shfl_xor(acc.y, 16);
    acc.z += __shfl_xor(acc.z, 16); acc.w += __shfl_xor(acc.w, 16);
    acc.x += __shfl_xor(acc.x, 32); acc.y += __shfl_xor(acc.y, 32);
    acc.z += __shfl_xor(acc.z, 32); acc.w += __shfl_xor(acc.w, 32);
    if (j == 0 && q < 13)
        *reinterpret_cast<float4*>(agg + (size_t)w * PC + q * 4) = acc;
}

// GRUCell: one thread per (node, out-channel); agg/hout rows padded to PC, h stride hs
__global__ __launch_bounds__(256) void gru_kernel(const float* __restrict__ agg,
                                                  const float* __restrict__ h, int hs,
                                                  const float* __restrict__ w_ih,
                                                  const float* __restrict__ w_hh,
                                                  const float* __restrict__ b_ih,
                                                  const float* __restrict__ b_hh,
                                                  float* __restrict__ hout) {
    __shared__ float s_wih[C3 * C];   // 30 KB
    __shared__ float s_whh[C3 * C];   // 30 KB
    for (int i = threadIdx.x; i < C3 * C; i += 256) {
        s_wih[i] = w_ih[i];
        s_whh[i] = w_hh[i];
    }
    __syncthreads();
    int t = blockIdx.x * 256 + threadIdx.x;
    if (t >= NC) return;
    int n = t / C, c = t - n * C;
    const float* ar = agg + (size_t)n * PC;
    const float* hr = h + (size_t)n * hs;
    float ir = 0.f, iz = 0.f, inn = 0.f, hr_ = 0.f, hz = 0.f, hn = 0.f;
#pragma unroll
    for (int k = 0; k < C; ++k) {
        float a = ar[k], hv = hr[k];
        ir  = fmaf(a,  s_wih[c * C + k],            ir);
        iz  = fmaf(a,  s_wih[(C + c) * C + k],      iz);
        inn = fmaf(a,  s_wih[(2 * C + c) * C + k],  inn);
        hr_ = fmaf(hv, s_whh[c * C + k],            hr_);
        hz  = fmaf(hv, s_whh[(C + c) * C + k],      hz);
        hn  = fmaf(hv, s_whh[(2 * C + c) * C + k],  hn);
    }
    ir  += b_ih[c];         hr_ += b_hh[c];
    iz  += b_ih[C + c];     hz  += b_hh[C + c];
    inn += b_ih[2 * C + c]; hn  += b_hh[2 * C + c];
    float r = 1.f / (1.f + expf(-(ir + hr_)));
    float z = 1.f / (1.f + expf(-(iz + hz)));
    float nn = tanhf(inn + r * hn);
    hout[(size_t)n * PC + c] = (1.f - z) * nn + z * hr[c];
}

// out[n,c] = sum_k relu(h[n,k]) * lin_w[c,k] + lin_b[c]; h padded PC, out dense C
__global__ __launch_bounds__(256) void out_kernel(const float* __restrict__ h,
                                                  const float* __restrict__ lin_w,
                                                  const float* __restrict__ lin_b,
                                                  float* __restrict__ out) {
    __shared__ float sW[C * C];
    for (int i = threadIdx.x; i < C * C; i += 256) sW[i] = lin_w[i];
    __syncthreads();
    int t = blockIdx.x * 256 + threadIdx.x;
    if (t >= NC) return;
    int n = t / C, c = t - n * C;
    const float* hr = h + (size_t)n * PC;
    float acc = lin_b[c];
#pragma unroll
    for (int k = 0; k < C; ++k) {
        float v = hr[k];
        v = v > 0.f ? v : 0.f;
        acc = fmaf(v, sW[c * C + k], acc);
    }
    out[t] = acc;
}

extern "C" void kernel_launch(void* const* d_in, const int* in_sizes, int n_in,
                              void* d_out, int out_size, void* d_ws, size_t ws_size,
                              hipStream_t stream) {
    const float* x      = (const float*)d_in[0];
    const int*   ei     = (const int*)  d_in[1];   // [2, E]
    const float* conv_w = (const float*)d_in[3];   // [3, C, C]
    const float* w_ih   = (const float*)d_in[4];
    const float* w_hh   = (const float*)d_in[5];
    const float* b_ih   = (const float*)d_in[6];
    const float* b_hh   = (const float*)d_in[7];
    const float* lin_w  = (const float*)d_in[9];
    const float* lin_b  = (const float*)d_in[10];
    float* out = (float*)d_out;

    float* ws   = (float*)d_ws;
    float* bufX = ws;                  // NCP floats (5.6M)
    float* bufY = ws + NCP;            // NCP
    float* bufZ = ws + 2 * (size_t)NCP; // NCP
    int* col       = (int*)(ws + 3 * (size_t)NCP);   // 3.2M
    int* rowptr    = col + N_EDGES;                  // 100001
    int* cursor    = rowptr + N_NODES + 1;           // 100001 (also deg)
    int* blockSums = cursor + N_NODES + 1;           // 391

    const int nodeBlocks  = (NC + 255) / 256;
    const int nodeBlocksP = (NCP + 255) / 256;
    const int edgeBlocks  = (N_EDGES + 255) / 256;
    const int waveBlocks  = (N_NODES * 64 + 255) / 256;

    // ---- CSR build (deg lives in `cursor`) ----
    hipMemsetAsync(cursor, 0, (size_t)(N_NODES + 1) * sizeof(int), stream);
    deg_kernel<<<edgeBlocks, 256, 0, stream>>>(ei, cursor);
    scan1_kernel<<<SCAN_BLOCKS, 256, 0, stream>>>(cursor, rowptr, blockSums);
    scan2_kernel<<<1, 512, 0, stream>>>(blockSums);
    scan3_kernel<<<SCAN_BLOCKS, 256, 0, stream>>>(rowptr, blockSums, cursor);
    fill_kernel<<<edgeBlocks, 256, 0, stream>>>(ei, cursor, col);

    // ---- 3 layers, buffer rotation: h0=x (stride C), later h stride PC ----
    conv_kernel<<<nodeBlocksP, 256, 0, stream>>>(x, C, conv_w + 0 * C * C, bufX);
    gather_kernel<<<waveBlocks, 256, 0, stream>>>(bufX, rowptr, col, bufY);
    gru_kernel<<<nodeBlocks, 256, 0, stream>>>(bufY, x, C, w_ih, w_hh, b_ih, b_hh, bufZ);

    conv_kernel<<<nodeBlocksP, 256, 0, stream>>>(bufZ, PC, conv_w + 1 * C * C, bufX);
    gather_kernel<<<waveBlocks, 256, 0, stream>>>(bufX, rowptr, col, bufY);
    gru_kernel<<<nodeBlocks, 256, 0, stream>>>(bufY, bufZ, PC, w_ih, w_hh, b_ih, b_hh, bufX);

    conv_kernel<<<nodeBlocksP, 256, 0, stream>>>(bufX, PC, conv_w + 2 * C * C, bufZ);
    gather_kernel<<<waveBlocks, 256, 0, stream>>>(bufZ, rowptr, col, bufY);
    gru_kernel<<<nodeBlocks, 256, 0, stream>>>(bufY, bufX, PC, w_ih, w_hh, b_ih, b_hh, bufZ);

    out_kernel<<<nodeBlocks, 256, 0, stream>>>(bufZ, lin_w, lin_b, out);
}